// Round 1
// baseline (240.616 us; speedup 1.0000x reference)
//
#include <hip/hip_runtime.h>

// LNCC DEBUG1: num = (tp_sum - (p_sum/729)*t_sum)^2 + 1e-5, 9^3 box sums, SAME zero pad.
// Fused single-pass kernel: per-block 32x32 xy tile marching a 32-deep z chunk.
// Per plane: global->registers row-sums (x), LDS transpose, col-sums (y), then a
// 9-deep register ring (unrolled) for the z dimension.

#define N 192
#define TILE 32
#define ZCHUNK 32
#define NT 6      // 192/32 tiles per dim
#define NZC 6     // 192/32 z chunks

__global__ __launch_bounds__(1024, 4)
void lncc_kernel(const float* __restrict__ t_in,
                 const float* __restrict__ p_in,
                 float* __restrict__ out)
{
    // rowT[f][x][ry]: transposed row-sums, stride 44 (16B-aligned float4 rows)
    __shared__ __align__(16) float rowT[3 * 32 * 44];
    // pcol[f][y][x]: per-plane 2D (9x9) box sums
    __shared__ float pcol[3 * 32 * 32];

    const int bid = blockIdx.x;
    const int b   = bid / (NT * NT * NZC);
    int rem       = bid % (NT * NT * NZC);
    const int zc  = rem / (NT * NT);
    rem           = rem % (NT * NT);
    const int ty  = rem / NT;
    const int tx  = rem % NT;

    const int x0 = tx * TILE, y0 = ty * TILE, z0 = zc * ZCHUNK;
    const int tid = threadIdx.x;

    // ---- L (row-sum) phase decode: 3 fields x 40 rows x 8 x-quads = 960 slots
    const int  lf   = tid / 320;          // field: 0=t 1=p 2=tp (wave-uniform: 320=5*64)
    const int  ls   = tid - lf * 320;
    const int  lry  = ls >> 3;            // raw row 0..39
    const int  lxq  = ls & 7;             // x quad 0..7
    const int  lgy  = y0 - 4 + lry;
    const int  lgx0 = x0 - 4 + 4 * lxq;   // 16B-aligned quad base
    const bool lactive = (tid < 960);
    const bool lyok = ((unsigned)lgy < (unsigned)N);

    // ---- C (col-sum) phase decode: 3 fields x 8 y-quads x 32 x = 768 slots
    const int  cf = tid >> 8;             // wave-uniform (256=4*64)
    const int  cyq = (tid >> 5) & 7;
    const int  cx  = tid & 31;
    const bool cactive = (tid < 768);

    // ---- G (gather/ring) decode: thread owns output column (gx,gy)
    const int gx = tid & 31;
    const int gy = tid >> 5;

    const size_t plane = (size_t)N * N;
    const float* tb = t_in + (size_t)b * N * plane;
    const float* pb = p_in + (size_t)b * N * plane;
    float*       ob = out  + (size_t)b * N * plane;

    float ring_t[9], ring_p[9], ring_tp[9];
    float sum_t = 0.f, sum_p = 0.f, sum_tp = 0.f;
    #pragma unroll
    for (int i = 0; i < 9; ++i) { ring_t[i] = 0.f; ring_p[i] = 0.f; ring_tp[i] = 0.f; }

    #pragma unroll 1
    for (int k = 0; k < 5; ++k) {
      #pragma unroll
      for (int r = 0; r < 9; ++r) {
        const int zi = k * 9 + r;          // plane index within chunk pipeline
        const int zp = z0 - 4 + zi;        // global z of plane
        const bool pvalid = (zi < ZCHUNK + 8) && ((unsigned)zp < (unsigned)N);
        float Pt = 0.f, Pp = 0.f, Ptp = 0.f;
        if (pvalid) {   // block-uniform branch: barriers inside are safe
          // ---------- L: global loads + sliding 9-tap row sums (x) ----------
          if (lactive) {
            const float* rt = tb + (size_t)zp * plane + (size_t)lgy * N;
            const float* rp = pb + (size_t)zp * plane + (size_t)lgy * N;
            float v[12];
            #pragma unroll
            for (int q = 0; q < 3; ++q) {
              const int gxq = lgx0 + 4 * q;
              const bool ok = lyok && ((unsigned)gxq < (unsigned)N); // quads all-in/all-out
              float4 a = make_float4(0.f, 0.f, 0.f, 0.f);
              float4 c = make_float4(0.f, 0.f, 0.f, 0.f);
              if (ok) {
                if (lf != 1) a = *(const float4*)(rt + gxq);
                if (lf != 0) c = *(const float4*)(rp + gxq);
              }
              if (lf == 1) a = c;
              if (lf == 2) { a.x *= c.x; a.y *= c.y; a.z *= c.z; a.w *= c.w; }
              v[4*q+0] = a.x; v[4*q+1] = a.y; v[4*q+2] = a.z; v[4*q+3] = a.w;
            }
            float s0 = ((v[0]+v[1]) + (v[2]+v[3])) + ((v[4]+v[5]) + (v[6]+v[7])) + v[8];
            float s1 = s0 - v[0] + v[9];
            float s2 = s1 - v[1] + v[10];
            float s3 = s2 - v[2] + v[11];
            const int wb = (lf * 32 + 4 * lxq) * 44 + lry;  // transposed store
            rowT[wb      ] = s0;
            rowT[wb +  44] = s1;
            rowT[wb +  88] = s2;
            rowT[wb + 132] = s3;
          }
          __syncthreads();
          // ---------- C: sliding 9-tap col sums (y) via aligned b128 ----------
          if (cactive) {
            const float4* rq = (const float4*)&rowT[(cf * 32 + cx) * 44 + 4 * cyq];
            const float4 A = rq[0], B4 = rq[1], C4 = rq[2];
            const float w0=A.x,  w1=A.y,  w2=A.z,  w3=A.w;
            const float w4=B4.x, w5=B4.y, w6=B4.z, w7=B4.w;
            const float w8=C4.x, w9=C4.y, w10=C4.z, w11=C4.w;
            float c0 = ((w0+w1)+(w2+w3)) + ((w4+w5)+(w6+w7)) + w8;
            float c1 = c0 - w0 + w9;
            float c2 = c1 - w1 + w10;
            float c3 = c2 - w2 + w11;
            const int pbase = cf * 1024 + (4 * cyq) * 32 + cx;
            pcol[pbase     ] = c0;
            pcol[pbase + 32] = c1;
            pcol[pbase + 64] = c2;
            pcol[pbase + 96] = c3;
          }
          __syncthreads();
          // ---------- G: gather this column's plane sums ----------
          Pt  = pcol[       gy * 32 + gx];
          Pp  = pcol[1024 + gy * 32 + gx];
          Ptp = pcol[2048 + gy * 32 + gx];
        }
        // z-dimension sliding window via 9-deep register ring (static index r)
        sum_t  += Pt  - ring_t[r];  ring_t[r]  = Pt;
        sum_p  += Pp  - ring_p[r];  ring_p[r]  = Pp;
        sum_tp += Ptp - ring_tp[r]; ring_tp[r] = Ptp;
        if (zi >= 8 && zi < ZCHUNK + 8) {
          const int zout = zp - 4;
          const float cross = sum_tp - (sum_p * (1.0f / 729.0f)) * sum_t;
          ob[(size_t)zout * plane + (size_t)(y0 + gy) * N + (x0 + gx)]
              = cross * cross + 1e-5f;
        }
      }
    }
}

extern "C" void kernel_launch(void* const* d_in, const int* in_sizes, int n_in,
                              void* d_out, int out_size, void* d_ws, size_t ws_size,
                              hipStream_t stream) {
    const float* y_true = (const float*)d_in[0];
    const float* y_pred = (const float*)d_in[1];
    float* out = (float*)d_out;
    dim3 grid(2 * NT * NT * NZC);   // 432 blocks
    dim3 block(1024);
    hipLaunchKernelGGL(lncc_kernel, grid, block, 0, stream, y_true, y_pred, out);
}

// Round 3
// 211.879 us; speedup vs baseline: 1.1356x; 1.1356x over previous
//
#include <hip/hip_runtime.h>

// LNCC DEBUG1: num = (tp_sum - (p_sum/729)*t_sum)^2 + 1e-5, 9^3 box sums, SAME zero pad.
// R1-proven 2-barrier single-buffer structure + register prefetch (deferred consume).
// Per iteration i:
//   issue global loads(plane i+1) -> flight regs
//   RowSum(plane i) from cur regs -> rowT     | barrier
//   ColSum(plane i) rowT -> pcol              | barrier
//   Gather(plane i) pcol -> z-ring -> output
//   finalize: cur = (lf==2 ? t*p : field) from flight regs   (loads had ~full iter to land)
// Grid = 512 blocks exactly (2 clean rounds on 256 CUs, no remainder tail):
//   72 xy tiles; 8 tiles get 8 z-chunks (Z=24), 64 tiles get 7 z-chunks (Z=28/27).

#define N 192
#define RSTRIDE 46   // rowT stride: 2-way banks (free) + 8B-aligned float2 reads

__global__ __launch_bounds__(1024, 4)
void lncc_kernel(const float* __restrict__ t_in,
                 const float* __restrict__ p_in,
                 float* __restrict__ out)
{
    // rowT[f][x][ry]: transposed x-blurred row sums (single-buffered)
    __shared__ __align__(16) float rowT[3 * 32 * RSTRIDE];   // 17.3 KB
    // pcol[f][y][x]: per-plane 2D (9x9) box sums
    __shared__ float pcol[3 * 32 * 32];                      // 12 KB

    // ---- work assignment: 512 blocks = 72 xy tiles x {8 or 7} z-chunks ----
    const int bid = blockIdx.x;
    int xy, Z, z0;
    if (bid < 64) {                 // tiles 0..7: 8 chunks of Z=24
        xy = bid >> 3;
        Z  = 24;
        z0 = (bid & 7) * 24;
    } else {                        // tiles 8..71: 7 chunks (28,28,28,27,27,27,27)
        const int q  = bid - 64;
        xy = 8 + q / 7;
        const int zi = q % 7;
        if (zi < 3) { Z = 28; z0 = zi * 28; }
        else        { Z = 27; z0 = 84 + (zi - 3) * 27; }
    }
    const int b  = xy / 36;
    const int t6 = xy % 36;
    const int y0 = (t6 / 6) * 32, x0 = (t6 % 6) * 32;
    const int tid = threadIdx.x;

    // ---- L (row-sum) decode: 3 fields x 40 rows x 8 x-quads = 960 slots (15 waves)
    const int  lf   = tid / 320;          // 0=t 1=p 2=tp (wave-uniform: 320=5*64)
    const int  ls   = tid - lf * 320;
    const int  lry  = ls >> 3;            // raw row 0..39
    const int  lxq  = ls & 7;             // x quad 0..7
    const int  lgy  = y0 - 4 + lry;
    const int  lgx0 = x0 - 4 + 4 * lxq;   // 16B-aligned quad base
    const bool lactive = (tid < 960);
    const bool lyok = ((unsigned)lgy < (unsigned)N);

    // ---- C (col-sum) decode: 3 fields x 8 y-quads x 32 x = 768 slots (12 waves)
    const int  cf  = tid >> 8;
    const int  cyq = (tid >> 5) & 7;
    const int  cx  = tid & 31;
    const bool cactive = (tid < 768);

    // ---- G decode: thread owns output column (gx,gy)
    const int gx = tid & 31;
    const int gy = tid >> 5;

    const size_t plane = (size_t)N * N;
    const float* tb = t_in + (size_t)b * N * plane;
    const float* pb = p_in + (size_t)b * N * plane;
    float*       ob = out  + (size_t)b * N * plane
                           + (size_t)(y0 + gy) * N + (x0 + gx);

    float ring_t[9], ring_p[9], ring_tp[9];
    float sum_t = 0.f, sum_p = 0.f, sum_tp = 0.f;
    #pragma unroll
    for (int i = 0; i < 9; ++i) { ring_t[i] = 0.f; ring_p[i] = 0.f; ring_tp[i] = 0.f; }

    const float4 z4 = make_float4(0.f, 0.f, 0.f, 0.f);
    float4 cur0 = z4, cur1 = z4, cur2 = z4;     // row-sum-ready 12 floats for plane i

    // ---- prologue: load + finalize plane 0 (one exposed latency per block)
    {
        const int zp0 = z0 - 4;
        if (((unsigned)zp0 < (unsigned)N) && lactive && lyok) {
            const float* rt = tb + (size_t)zp0 * plane + (size_t)lgy * N;
            const float* rp = pb + (size_t)zp0 * plane + (size_t)lgy * N;
            float4 a[3], c[3];
            #pragma unroll
            for (int q = 0; q < 3; ++q) {
                a[q] = z4; c[q] = z4;
                const int gxq = lgx0 + 4 * q;
                if ((unsigned)gxq < (unsigned)N) {
                    a[q] = (lf == 1) ? *(const float4*)(rp + gxq)
                                     : *(const float4*)(rt + gxq);
                    if (lf == 2) c[q] = *(const float4*)(rp + gxq);
                }
            }
            if (lf == 2) {
                #pragma unroll
                for (int q = 0; q < 3; ++q) {
                    a[q].x *= c[q].x; a[q].y *= c[q].y;
                    a[q].z *= c[q].z; a[q].w *= c[q].w;
                }
            }
            cur0 = a[0]; cur1 = a[1]; cur2 = a[2];
        }
    }

    #pragma unroll 1
    for (int k = 0; k < 4; ++k) {
      #pragma unroll
      for (int r = 0; r < 9; ++r) {
        const int i  = k * 9 + r;
        const int zp = z0 - 4 + i;           // plane i
        const int zn = zp + 1;               // plane i+1
        const bool vi = (i < Z + 8)     && ((unsigned)zp < (unsigned)N);
        const bool vn = (i + 1 < Z + 8) && ((unsigned)zn < (unsigned)N);

        // ---- 1. issue loads for plane i+1 (consumed at step 5) ----
        float4 fa0 = z4, fa1 = z4, fa2 = z4, fc0 = z4, fc1 = z4, fc2 = z4;
        if (vn && lactive && lyok) {
            const float* rt = tb + (size_t)zn * plane + (size_t)lgy * N;
            const float* rp = pb + (size_t)zn * plane + (size_t)lgy * N;
            const int g0 = lgx0, g1 = lgx0 + 4, g2 = lgx0 + 8;
            if ((unsigned)g0 < (unsigned)N) {
                fa0 = (lf == 1) ? *(const float4*)(rp + g0) : *(const float4*)(rt + g0);
                if (lf == 2) fc0 = *(const float4*)(rp + g0);
            }
            if ((unsigned)g1 < (unsigned)N) {
                fa1 = (lf == 1) ? *(const float4*)(rp + g1) : *(const float4*)(rt + g1);
                if (lf == 2) fc1 = *(const float4*)(rp + g1);
            }
            if ((unsigned)g2 < (unsigned)N) {
                fa2 = (lf == 1) ? *(const float4*)(rp + g2) : *(const float4*)(rt + g2);
                if (lf == 2) fc2 = *(const float4*)(rp + g2);
            }
        }

        // ---- 2. RowSum(plane i) from cur -> rowT ----
        if (vi && lactive) {
            const float v0 = cur0.x, v1 = cur0.y, v2  = cur0.z, v3  = cur0.w;
            const float v4 = cur1.x, v5 = cur1.y, v6  = cur1.z, v7  = cur1.w;
            const float v8 = cur2.x, v9 = cur2.y, v10 = cur2.z, v11 = cur2.w;
            float s0 = ((v0+v1) + (v2+v3)) + ((v4+v5) + (v6+v7)) + v8;
            float s1 = s0 - v0 + v9;
            float s2 = s1 - v1 + v10;
            float s3 = s2 - v2 + v11;
            float* wp = &rowT[(lf * 32 + 4 * lxq) * RSTRIDE + lry];
            wp[0]           = s0;
            wp[RSTRIDE]     = s1;
            wp[2 * RSTRIDE] = s2;
            wp[3 * RSTRIDE] = s3;
        }
        __syncthreads();

        // ---- 3. ColSum(plane i): rowT -> pcol ----
        if (vi && cactive) {
            const float* rb = &rowT[(cf * 32 + cx) * RSTRIDE + 4 * cyq];
            const float2 u0 = *(const float2*)(rb + 0);
            const float2 u1 = *(const float2*)(rb + 2);
            const float2 u2 = *(const float2*)(rb + 4);
            const float2 u3 = *(const float2*)(rb + 6);
            const float2 u4 = *(const float2*)(rb + 8);
            const float2 u5 = *(const float2*)(rb + 10);
            const float w0=u0.x, w1=u0.y, w2=u1.x,  w3=u1.y;
            const float w4=u2.x, w5=u2.y, w6=u3.x,  w7=u3.y;
            const float w8=u4.x, w9=u4.y, w10=u5.x, w11=u5.y;
            float c0 = ((w0+w1)+(w2+w3)) + ((w4+w5)+(w6+w7)) + w8;
            float c1 = c0 - w0 + w9;
            float c2 = c1 - w1 + w10;
            float c3 = c2 - w2 + w11;
            float* pc = &pcol[cf * 1024 + (4 * cyq) * 32 + cx];
            pc[0]  = c0;
            pc[32] = c1;
            pc[64] = c2;
            pc[96] = c3;
        }
        __syncthreads();

        // ---- 4. Gather(plane i), z-ring (slot r == i%9), output ----
        float Pt = 0.f, Pp = 0.f, Ptp = 0.f;
        if (vi) {
            Pt  = pcol[       gy * 32 + gx];
            Pp  = pcol[1024 + gy * 32 + gx];
            Ptp = pcol[2048 + gy * 32 + gx];
        }
        sum_t  += Pt  - ring_t[r];  ring_t[r]  = Pt;
        sum_p  += Pp  - ring_p[r];  ring_p[r]  = Pp;
        sum_tp += Ptp - ring_tp[r]; ring_tp[r] = Ptp;
        if (i >= 8 && i < Z + 8) {
            const float cross = sum_tp - (sum_p * (1.0f / 729.0f)) * sum_t;
            ob[(size_t)(z0 + i - 8) * plane] = cross * cross + 1e-5f;
        }

        // ---- 5. finalize: cur = (lf==2 ? a*c : a)  (loads have landed by now) ----
        if (vn && lactive) {
            float4 A0 = fa0, A1 = fa1, A2 = fa2;
            if (lf == 2) {
                A0.x *= fc0.x; A0.y *= fc0.y; A0.z *= fc0.z; A0.w *= fc0.w;
                A1.x *= fc1.x; A1.y *= fc1.y; A1.z *= fc1.z; A1.w *= fc1.w;
                A2.x *= fc2.x; A2.y *= fc2.y; A2.z *= fc2.z; A2.w *= fc2.w;
            }
            cur0 = A0; cur1 = A1; cur2 = A2;
        }
      }
    }
}

extern "C" void kernel_launch(void* const* d_in, const int* in_sizes, int n_in,
                              void* d_out, int out_size, void* d_ws, size_t ws_size,
                              hipStream_t stream) {
    const float* y_true = (const float*)d_in[0];
    const float* y_pred = (const float*)d_in[1];
    float* out = (float*)d_out;
    dim3 grid(512);
    dim3 block(1024);
    hipLaunchKernelGGL(lncc_kernel, grid, block, 0, stream, y_true, y_pred, out);
}

// Round 4
// 210.517 us; speedup vs baseline: 1.1430x; 1.0065x over previous
//
#include <hip/hip_runtime.h>

// LNCC DEBUG1: num = (tp_sum - (p_sum/729)*t_sum)^2 + 1e-5, 9^3 box sums, SAME zero pad.
// R3 structure (2-barrier single-buffer, register prefetch) with ONE change:
// __syncthreads() -> raw { s_waitcnt lgkmcnt(0); s_barrier }.
// Rationale: HIP's __syncthreads emits s_waitcnt vmcnt(0) before s_barrier, force-
// draining the in-flight register prefetch loads ~100cyc after issue (twice per
// plane) and exposing full L2/HBM latency. The raw barrier drains only LDS
// (producer->consumer visibility needs exactly lgkmcnt(0)+s_barrier); the prefetch
// loads are register-destined (no cross-wave visibility needed; the compiler still
// inserts the same-wave vmcnt wait at the consume point in step 5).
// Barriers remain in block-uniform control flow (R3-proven, deterministic).

#define N 192
#define RSTRIDE 46   // rowT stride: 2-way banks (free) + 8B-aligned float2 reads

// LDS-only barrier: drain LDS ops, then barrier. No vmcnt drain.
#define LDS_BARRIER() asm volatile("s_waitcnt lgkmcnt(0)\n\ts_barrier" ::: "memory")

__global__ __launch_bounds__(1024, 4)
void lncc_kernel(const float* __restrict__ t_in,
                 const float* __restrict__ p_in,
                 float* __restrict__ out)
{
    // rowT[f][x][ry]: transposed x-blurred row sums (single-buffered)
    __shared__ __align__(16) float rowT[3 * 32 * RSTRIDE];   // 17.3 KB
    // pcol[f][y][x]: per-plane 2D (9x9) box sums
    __shared__ float pcol[3 * 32 * 32];                      // 12 KB

    // ---- work assignment: 512 blocks = 72 xy tiles x {8 or 7} z-chunks ----
    const int bid = blockIdx.x;
    int xy, Z, z0;
    if (bid < 64) {                 // tiles 0..7: 8 chunks of Z=24
        xy = bid >> 3;
        Z  = 24;
        z0 = (bid & 7) * 24;
    } else {                        // tiles 8..71: 7 chunks (28,28,28,27,27,27,27)
        const int q  = bid - 64;
        xy = 8 + q / 7;
        const int zi = q % 7;
        if (zi < 3) { Z = 28; z0 = zi * 28; }
        else        { Z = 27; z0 = 84 + (zi - 3) * 27; }
    }
    const int b  = xy / 36;
    const int t6 = xy % 36;
    const int y0 = (t6 / 6) * 32, x0 = (t6 % 6) * 32;
    const int tid = threadIdx.x;

    // ---- L (row-sum) decode: 3 fields x 40 rows x 8 x-quads = 960 slots (15 waves)
    const int  lf   = tid / 320;          // 0=t 1=p 2=tp (wave-uniform: 320=5*64)
    const int  ls   = tid - lf * 320;
    const int  lry  = ls >> 3;            // raw row 0..39
    const int  lxq  = ls & 7;             // x quad 0..7
    const int  lgy  = y0 - 4 + lry;
    const int  lgx0 = x0 - 4 + 4 * lxq;   // 16B-aligned quad base
    const bool lactive = (tid < 960);
    const bool lyok = ((unsigned)lgy < (unsigned)N);

    // ---- C (col-sum) decode: 3 fields x 8 y-quads x 32 x = 768 slots (12 waves)
    const int  cf  = tid >> 8;
    const int  cyq = (tid >> 5) & 7;
    const int  cx  = tid & 31;
    const bool cactive = (tid < 768);

    // ---- G decode: thread owns output column (gx,gy)
    const int gx = tid & 31;
    const int gy = tid >> 5;

    const size_t plane = (size_t)N * N;
    const float* tb = t_in + (size_t)b * N * plane;
    const float* pb = p_in + (size_t)b * N * plane;
    float*       ob = out  + (size_t)b * N * plane
                           + (size_t)(y0 + gy) * N + (x0 + gx);

    float ring_t[9], ring_p[9], ring_tp[9];
    float sum_t = 0.f, sum_p = 0.f, sum_tp = 0.f;
    #pragma unroll
    for (int i = 0; i < 9; ++i) { ring_t[i] = 0.f; ring_p[i] = 0.f; ring_tp[i] = 0.f; }

    const float4 z4 = make_float4(0.f, 0.f, 0.f, 0.f);
    float4 cur0 = z4, cur1 = z4, cur2 = z4;     // row-sum-ready 12 floats for plane i

    // ---- prologue: load + finalize plane 0 (one exposed latency per block)
    {
        const int zp0 = z0 - 4;
        if (((unsigned)zp0 < (unsigned)N) && lactive && lyok) {
            const float* rt = tb + (size_t)zp0 * plane + (size_t)lgy * N;
            const float* rp = pb + (size_t)zp0 * plane + (size_t)lgy * N;
            float4 a[3], c[3];
            #pragma unroll
            for (int q = 0; q < 3; ++q) {
                a[q] = z4; c[q] = z4;
                const int gxq = lgx0 + 4 * q;
                if ((unsigned)gxq < (unsigned)N) {
                    a[q] = (lf == 1) ? *(const float4*)(rp + gxq)
                                     : *(const float4*)(rt + gxq);
                    if (lf == 2) c[q] = *(const float4*)(rp + gxq);
                }
            }
            if (lf == 2) {
                #pragma unroll
                for (int q = 0; q < 3; ++q) {
                    a[q].x *= c[q].x; a[q].y *= c[q].y;
                    a[q].z *= c[q].z; a[q].w *= c[q].w;
                }
            }
            cur0 = a[0]; cur1 = a[1]; cur2 = a[2];
        }
    }

    #pragma unroll 1
    for (int k = 0; k < 4; ++k) {
      #pragma unroll
      for (int r = 0; r < 9; ++r) {
        const int i  = k * 9 + r;
        const int zp = z0 - 4 + i;           // plane i
        const int zn = zp + 1;               // plane i+1
        const bool vi = (i < Z + 8)     && ((unsigned)zp < (unsigned)N);
        const bool vn = (i + 1 < Z + 8) && ((unsigned)zn < (unsigned)N);

        // ---- 1. issue loads for plane i+1 (consumed at step 5) ----
        float4 fa0 = z4, fa1 = z4, fa2 = z4, fc0 = z4, fc1 = z4, fc2 = z4;
        if (vn && lactive && lyok) {
            const float* rt = tb + (size_t)zn * plane + (size_t)lgy * N;
            const float* rp = pb + (size_t)zn * plane + (size_t)lgy * N;
            const int g0 = lgx0, g1 = lgx0 + 4, g2 = lgx0 + 8;
            if ((unsigned)g0 < (unsigned)N) {
                fa0 = (lf == 1) ? *(const float4*)(rp + g0) : *(const float4*)(rt + g0);
                if (lf == 2) fc0 = *(const float4*)(rp + g0);
            }
            if ((unsigned)g1 < (unsigned)N) {
                fa1 = (lf == 1) ? *(const float4*)(rp + g1) : *(const float4*)(rt + g1);
                if (lf == 2) fc1 = *(const float4*)(rp + g1);
            }
            if ((unsigned)g2 < (unsigned)N) {
                fa2 = (lf == 1) ? *(const float4*)(rp + g2) : *(const float4*)(rt + g2);
                if (lf == 2) fc2 = *(const float4*)(rp + g2);
            }
        }

        // ---- 2. RowSum(plane i) from cur -> rowT ----
        if (vi && lactive) {
            const float v0 = cur0.x, v1 = cur0.y, v2  = cur0.z, v3  = cur0.w;
            const float v4 = cur1.x, v5 = cur1.y, v6  = cur1.z, v7  = cur1.w;
            const float v8 = cur2.x, v9 = cur2.y, v10 = cur2.z, v11 = cur2.w;
            float s0 = ((v0+v1) + (v2+v3)) + ((v4+v5) + (v6+v7)) + v8;
            float s1 = s0 - v0 + v9;
            float s2 = s1 - v1 + v10;
            float s3 = s2 - v2 + v11;
            float* wp = &rowT[(lf * 32 + 4 * lxq) * RSTRIDE + lry];
            wp[0]           = s0;
            wp[RSTRIDE]     = s1;
            wp[2 * RSTRIDE] = s2;
            wp[3 * RSTRIDE] = s3;
        }
        LDS_BARRIER();

        // ---- 3. ColSum(plane i): rowT -> pcol ----
        if (vi && cactive) {
            const float* rb = &rowT[(cf * 32 + cx) * RSTRIDE + 4 * cyq];
            const float2 u0 = *(const float2*)(rb + 0);
            const float2 u1 = *(const float2*)(rb + 2);
            const float2 u2 = *(const float2*)(rb + 4);
            const float2 u3 = *(const float2*)(rb + 6);
            const float2 u4 = *(const float2*)(rb + 8);
            const float2 u5 = *(const float2*)(rb + 10);
            const float w0=u0.x, w1=u0.y, w2=u1.x,  w3=u1.y;
            const float w4=u2.x, w5=u2.y, w6=u3.x,  w7=u3.y;
            const float w8=u4.x, w9=u4.y, w10=u5.x, w11=u5.y;
            float c0 = ((w0+w1)+(w2+w3)) + ((w4+w5)+(w6+w7)) + w8;
            float c1 = c0 - w0 + w9;
            float c2 = c1 - w1 + w10;
            float c3 = c2 - w2 + w11;
            float* pc = &pcol[cf * 1024 + (4 * cyq) * 32 + cx];
            pc[0]  = c0;
            pc[32] = c1;
            pc[64] = c2;
            pc[96] = c3;
        }
        LDS_BARRIER();

        // ---- 4. Gather(plane i), z-ring (slot r == i%9), output ----
        float Pt = 0.f, Pp = 0.f, Ptp = 0.f;
        if (vi) {
            Pt  = pcol[       gy * 32 + gx];
            Pp  = pcol[1024 + gy * 32 + gx];
            Ptp = pcol[2048 + gy * 32 + gx];
        }
        sum_t  += Pt  - ring_t[r];  ring_t[r]  = Pt;
        sum_p  += Pp  - ring_p[r];  ring_p[r]  = Pp;
        sum_tp += Ptp - ring_tp[r]; ring_tp[r] = Ptp;
        if (i >= 8 && i < Z + 8) {
            const float cross = sum_tp - (sum_p * (1.0f / 729.0f)) * sum_t;
            ob[(size_t)(z0 + i - 8) * plane] = cross * cross + 1e-5f;
        }

        // ---- 5. finalize: cur = (lf==2 ? a*c : a)  (loads have landed by now) ----
        if (vn && lactive) {
            float4 A0 = fa0, A1 = fa1, A2 = fa2;
            if (lf == 2) {
                A0.x *= fc0.x; A0.y *= fc0.y; A0.z *= fc0.z; A0.w *= fc0.w;
                A1.x *= fc1.x; A1.y *= fc1.y; A1.z *= fc1.z; A1.w *= fc1.w;
                A2.x *= fc2.x; A2.y *= fc2.y; A2.z *= fc2.z; A2.w *= fc2.w;
            }
            cur0 = A0; cur1 = A1; cur2 = A2;
        }
      }
    }
}

extern "C" void kernel_launch(void* const* d_in, const int* in_sizes, int n_in,
                              void* d_out, int out_size, void* d_ws, size_t ws_size,
                              hipStream_t stream) {
    const float* y_true = (const float*)d_in[0];
    const float* y_pred = (const float*)d_in[1];
    float* out = (float*)d_out;
    dim3 grid(512);
    dim3 block(1024);
    hipLaunchKernelGGL(lncc_kernel, grid, block, 0, stream, y_true, y_pred, out);
}